// Round 10
// baseline (54.181 us; speedup 1.0000x reference)
//
#include <hip/hip_runtime.h>
#include <math.h>

// x: [28, 256, 128, 128] fp32; group lens {4,3,4,4,3,4,2,4} (starts = prefix).
// Group slab [L,256,16384] viewed [256,L,16384]: cluster c uses slab rows
// c*L..c*L+L-1 (16384 floats each). out[g, c*L+q, :] =
//   sum_k softmax_k(dot(row_q,row_k)/16) * row_k  for c*L+q < 256.
//
// 250 blocks x 1024 threads (<=1 block/CU), each a static chain of clusters:
//   b<160:   (L4,L4)        1024 KB
//   b<217:   (L3,L3,L3)     1152 KB
//   b==217:  (L3,L2,L2)      896 KB
//   b<249:   (L2,L2,L2,L2)  1024 KB
//   b==249:  (L2,L2)         512 KB
// Per cluster: whole cluster in registers (NT loads, no LLC allocation) ->
// gram in-register -> 2-level reduce -> per-thread softmax -> weighted sum ->
// NT stores. x read once, out written once, zero cache dependence.

#define DIMD 16384
#define NCH  256
#define ROW4 4096   // float4 per row

typedef float f32x4 __attribute__((ext_vector_type(4)));

template <int L>
__device__ __forceinline__ void do_cluster(const float* __restrict__ base,
                                           float* __restrict__ outp,
                                           int nout, int tid,
                                           float (*__restrict__ red)[10],
                                           float* __restrict__ S_l) {
    constexpr int NP  = L * (L + 1) / 2;
    constexpr int PER = ROW4 / 1024;      // 4 float4 per row per thread

    const int lane = tid & 63, wave = tid >> 6;

    // ---- load whole cluster into registers (coalesced, nontemporal) ----
    f32x4 v[L][PER];
    #pragma unroll
    for (int k = 0; k < L; ++k) {
        const f32x4* row = (const f32x4*)(base + (size_t)k * DIMD);
        #pragma unroll
        for (int i = 0; i < PER; ++i)
            v[k][i] = __builtin_nontemporal_load(row + i * 1024 + tid);
    }

    // ---- gram partials in-register ----
    float acc[NP];
    #pragma unroll
    for (int p = 0; p < NP; ++p) acc[p] = 0.f;
    #pragma unroll
    for (int i = 0; i < PER; ++i) {
        int idx = 0;
        #pragma unroll
        for (int a = 0; a < L; ++a) {
            #pragma unroll
            for (int b = a; b < L; ++b) {
                acc[idx] = fmaf(v[a][i].x, v[b][i].x, acc[idx]);
                acc[idx] = fmaf(v[a][i].y, v[b][i].y, acc[idx]);
                acc[idx] = fmaf(v[a][i].z, v[b][i].z, acc[idx]);
                acc[idx] = fmaf(v[a][i].w, v[b][i].w, acc[idx]);
                ++idx;
            }
        }
    }

    // ---- reduce: wave shuffle, then 16-wave LDS reduce ----
    #pragma unroll
    for (int p = 0; p < NP; ++p) {
        float s = acc[p];
        #pragma unroll
        for (int off = 32; off > 0; off >>= 1) s += __shfl_down(s, off, 64);
        if (lane == 0) red[wave][p] = s;
    }
    __syncthreads();
    if (tid < NP) {
        float s = 0.f;
        #pragma unroll
        for (int w = 0; w < 16; ++w) s += red[w][tid];
        S_l[tid] = s * 0.0625f;   // 1/sqrt(256)
    }
    __syncthreads();

    // ---- redundant per-thread softmax (tiny) ----
    float S[L][L];
    {
        int idx = 0;
        #pragma unroll
        for (int a = 0; a < L; ++a)
            #pragma unroll
            for (int b = a; b < L; ++b) { const float s = S_l[idx]; S[a][b] = s; S[b][a] = s; ++idx; }
    }
    float W[L][L];
    #pragma unroll
    for (int q = 0; q < L; ++q) {
        float m = S[q][0];
        #pragma unroll
        for (int k = 1; k < L; ++k) m = fmaxf(m, S[q][k]);
        float den = 0.f;
        #pragma unroll
        for (int k = 0; k < L; ++k) { W[q][k] = expf(S[q][k] - m); den += W[q][k]; }
        const float inv = 1.0f / den;
        #pragma unroll
        for (int k = 0; k < L; ++k) W[q][k] *= inv;
    }

    // ---- weighted sum from registers, NT store ----
    for (int q = 0; q < nout; ++q) {
        f32x4* orow = (f32x4*)(outp + (size_t)q * DIMD);
        #pragma unroll
        for (int i = 0; i < PER; ++i) {
            f32x4 o = {0.f, 0.f, 0.f, 0.f};
            #pragma unroll
            for (int k = 0; k < L; ++k) {
                const float w = W[q][k];
                o.x = fmaf(w, v[k][i].x, o.x);
                o.y = fmaf(w, v[k][i].y, o.y);
                o.z = fmaf(w, v[k][i].z, o.z);
                o.w = fmaf(w, v[k][i].w, o.w);
            }
            __builtin_nontemporal_store(o, orow + i * 1024 + tid);
        }
    }
}

// slot s of block b -> (g, c, L); false if chain ends.
__device__ __forceinline__ bool chain_slot(int b, int s, int& g, int& c, int& L) {
    const int g4[5] = {0, 2, 3, 5, 7};
    if (b < 160) {                         // (L4, L4)
        if (s >= 2) return false;
        const int i = b * 2 + s;           // 0..319
        g = g4[i >> 6]; c = i & 63; L = 4;
        return true;
    }
    if (b < 217) {                         // (L3, L3, L3)
        if (s >= 3) return false;
        const int j = (b - 160) * 3 + s;   // 0..170
        g = (j < 86) ? 1 : 4; c = (j < 86) ? j : j - 86; L = 3;
        return true;
    }
    if (b == 217) {                        // (L3, L2, L2)
        if (s == 0) { g = 4; c = 85; L = 3; return true; }   // L3 index 171
        if (s <= 2) { g = 6; c = s - 1; L = 2; return true; }
        return false;
    }
    if (b < 249) {                         // (L2 x4), c in [2,126)
        if (s >= 4) return false;
        g = 6; c = 2 + (b - 218) * 4 + s; L = 2;
        return true;
    }
    // b == 249: (L2, L2)
    if (s >= 2) return false;
    g = 6; c = 126 + s; L = 2;
    return true;
}

__global__ __launch_bounds__(1024, 4) void attfusion_chain(const float* __restrict__ x,
                                                           float* __restrict__ out) {
    __shared__ float red[16][10];
    __shared__ float S_l[10];
    const int starts[8] = {0, 4, 7, 11, 15, 18, 22, 24};
    const int b = blockIdx.x;
    const int tid = threadIdx.x;

    #pragma unroll 1
    for (int s = 0; s < 4; ++s) {
        int g, c, L;
        if (!chain_slot(b, s, g, c, L)) break;
        const float* base = x + ((size_t)starts[g] * NCH + (size_t)c * L) * DIMD;
        float* outp = out + ((size_t)g * NCH + (size_t)c * L) * DIMD;
        const int nout = min(L, NCH - c * L);
        if (L == 4)      do_cluster<4>(base, outp, nout, tid, red, S_l);
        else if (L == 3) do_cluster<3>(base, outp, nout, tid, red, S_l);
        else             do_cluster<2>(base, outp, nout, tid, red, S_l);
    }
}

extern "C" void kernel_launch(void* const* d_in, const int* in_sizes, int n_in,
                              void* d_out, int out_size, void* d_ws, size_t ws_size,
                              hipStream_t stream) {
    const float* x = (const float*)d_in[0];
    float* out = (float*)d_out;
    attfusion_chain<<<dim3(250), dim3(1024), 0, stream>>>(x, out);
}

// Round 11
// 46.774 us; speedup vs baseline: 1.1584x; 1.1584x over previous
//
#include <hip/hip_runtime.h>
#include <math.h>

// x: [28, 256, 128, 128] fp32; group lens {4,3,4,4,3,4,2,4} (starts = prefix).
// Group slab [L,256,16384] viewed [256,L,16384]: cluster c uses slab rows
// c*L..c*L+L-1 (16384 floats each). out[g, c*L+q, :] =
//   sum_k softmax_k(dot(row_q,row_k)/16) * row_k  for c*L+q < 256.
//
// 250 blocks x 1024 threads (<=1 block/CU), each a static chain of clusters:
//   b<160: (L4,L4) | b<217: (L3,L3,L3) | b==217: (L3,L2,L2)
//   b<249: (L2 x4) | b==249: (L2,L2)
// Per cluster: whole cluster in registers via normal cached loads (R10's NT
// loads cost ~7us — non-cached read path is slower than allocating), gram
// in-register -> 2-level reduce -> per-thread softmax -> weighted sum -> NT
// stores (don't pollute LLC with out).

#define DIMD 16384
#define NCH  256
#define ROW4 4096   // float4 per row

typedef float f32x4 __attribute__((ext_vector_type(4)));

template <int L>
__device__ __forceinline__ void do_cluster(const float* __restrict__ base,
                                           float* __restrict__ outp,
                                           int nout, int tid,
                                           float (*__restrict__ red)[10],
                                           float* __restrict__ S_l) {
    constexpr int NP  = L * (L + 1) / 2;
    constexpr int PER = ROW4 / 1024;      // 4 float4 per row per thread

    const int lane = tid & 63, wave = tid >> 6;

    // ---- load whole cluster into registers (coalesced, cached) ----
    float4 v[L][PER];
    #pragma unroll
    for (int k = 0; k < L; ++k) {
        const float4* row = (const float4*)(base + (size_t)k * DIMD);
        #pragma unroll
        for (int i = 0; i < PER; ++i) v[k][i] = row[i * 1024 + tid];
    }

    // ---- gram partials in-register ----
    float acc[NP];
    #pragma unroll
    for (int p = 0; p < NP; ++p) acc[p] = 0.f;
    #pragma unroll
    for (int i = 0; i < PER; ++i) {
        int idx = 0;
        #pragma unroll
        for (int a = 0; a < L; ++a) {
            #pragma unroll
            for (int b = a; b < L; ++b) {
                acc[idx] = fmaf(v[a][i].x, v[b][i].x, acc[idx]);
                acc[idx] = fmaf(v[a][i].y, v[b][i].y, acc[idx]);
                acc[idx] = fmaf(v[a][i].z, v[b][i].z, acc[idx]);
                acc[idx] = fmaf(v[a][i].w, v[b][i].w, acc[idx]);
                ++idx;
            }
        }
    }

    // ---- reduce: wave shuffle, then 16-wave LDS reduce ----
    #pragma unroll
    for (int p = 0; p < NP; ++p) {
        float s = acc[p];
        #pragma unroll
        for (int off = 32; off > 0; off >>= 1) s += __shfl_down(s, off, 64);
        if (lane == 0) red[wave][p] = s;
    }
    __syncthreads();
    if (tid < NP) {
        float s = 0.f;
        #pragma unroll
        for (int w = 0; w < 16; ++w) s += red[w][tid];
        S_l[tid] = s * 0.0625f;   // 1/sqrt(256)
    }
    __syncthreads();

    // ---- redundant per-thread softmax (tiny) ----
    float S[L][L];
    {
        int idx = 0;
        #pragma unroll
        for (int a = 0; a < L; ++a)
            #pragma unroll
            for (int b = a; b < L; ++b) { const float s = S_l[idx]; S[a][b] = s; S[b][a] = s; ++idx; }
    }
    float W[L][L];
    #pragma unroll
    for (int q = 0; q < L; ++q) {
        float m = S[q][0];
        #pragma unroll
        for (int k = 1; k < L; ++k) m = fmaxf(m, S[q][k]);
        float den = 0.f;
        #pragma unroll
        for (int k = 0; k < L; ++k) { W[q][k] = expf(S[q][k] - m); den += W[q][k]; }
        const float inv = 1.0f / den;
        #pragma unroll
        for (int k = 0; k < L; ++k) W[q][k] *= inv;
    }

    // ---- weighted sum from registers, NT store ----
    for (int q = 0; q < nout; ++q) {
        f32x4* orow = (f32x4*)(outp + (size_t)q * DIMD);
        #pragma unroll
        for (int i = 0; i < PER; ++i) {
            f32x4 o = {0.f, 0.f, 0.f, 0.f};
            #pragma unroll
            for (int k = 0; k < L; ++k) {
                const float w = W[q][k];
                o.x = fmaf(w, v[k][i].x, o.x);
                o.y = fmaf(w, v[k][i].y, o.y);
                o.z = fmaf(w, v[k][i].z, o.z);
                o.w = fmaf(w, v[k][i].w, o.w);
            }
            __builtin_nontemporal_store(o, orow + i * 1024 + tid);
        }
    }
}

// slot s of block b -> (g, c, L); false if chain ends.
__device__ __forceinline__ bool chain_slot(int b, int s, int& g, int& c, int& L) {
    const int g4[5] = {0, 2, 3, 5, 7};
    if (b < 160) {                         // (L4, L4)
        if (s >= 2) return false;
        const int i = b * 2 + s;           // 0..319
        g = g4[i >> 6]; c = i & 63; L = 4;
        return true;
    }
    if (b < 217) {                         // (L3, L3, L3)
        if (s >= 3) return false;
        const int j = (b - 160) * 3 + s;   // 0..170
        g = (j < 86) ? 1 : 4; c = (j < 86) ? j : j - 86; L = 3;
        return true;
    }
    if (b == 217) {                        // (L3, L2, L2)
        if (s == 0) { g = 4; c = 85; L = 3; return true; }   // L3 index 171
        if (s <= 2) { g = 6; c = s - 1; L = 2; return true; }
        return false;
    }
    if (b < 249) {                         // (L2 x4), c in [2,126)
        if (s >= 4) return false;
        g = 6; c = 2 + (b - 218) * 4 + s; L = 2;
        return true;
    }
    // b == 249: (L2, L2)
    if (s >= 2) return false;
    g = 6; c = 126 + s; L = 2;
    return true;
}

__global__ __launch_bounds__(1024, 4) void attfusion_chain(const float* __restrict__ x,
                                                           float* __restrict__ out) {
    __shared__ float red[16][10];
    __shared__ float S_l[10];
    const int starts[8] = {0, 4, 7, 11, 15, 18, 22, 24};
    const int b = blockIdx.x;
    const int tid = threadIdx.x;

    #pragma unroll 1
    for (int s = 0; s < 4; ++s) {
        int g, c, L;
        if (!chain_slot(b, s, g, c, L)) break;
        const float* base = x + ((size_t)starts[g] * NCH + (size_t)c * L) * DIMD;
        float* outp = out + ((size_t)g * NCH + (size_t)c * L) * DIMD;
        const int nout = min(L, NCH - c * L);
        if (L == 4)      do_cluster<4>(base, outp, nout, tid, red, S_l);
        else if (L == 3) do_cluster<3>(base, outp, nout, tid, red, S_l);
        else             do_cluster<2>(base, outp, nout, tid, red, S_l);
    }
}

extern "C" void kernel_launch(void* const* d_in, const int* in_sizes, int n_in,
                              void* d_out, int out_size, void* d_ws, size_t ws_size,
                              hipStream_t stream) {
    const float* x = (const float*)d_in[0];
    float* out = (float*)d_out;
    attfusion_chain<<<dim3(250), dim3(1024), 0, stream>>>(x, out);
}